// Round 3
// baseline (174.811 us; speedup 1.0000x reference)
//
#include <hip/hip_runtime.h>
#include <float.h>

#define HW    4096      // H*W
#define NC    64        // channels / latent dim
#define NK    1024      // codebook entries
#define NB    32        // batch
#define NPIX  (NB*HW)   // 131072 pixels
#define TOTAL (NPIX*NC) // 8388608 output elements of z_q
#define PPB   128       // pixels per block (16 per wave, 8 waves)

// bf16 hi/lo split score error bound ~1.4e-3 worst case; MARGIN 8e-3 gives
// >4x safety (validated rounds 4-9, absmax 0). gap2<MARGIN (incl. any exact
// fp32 tie) -> cooperative exact fp64 full rescan (~0.13%/pixel).
#define MARGIN 8e-3f

typedef __attribute__((ext_vector_type(8))) short short8;   // 8 bf16 (4 VGPRs)
typedef __attribute__((ext_vector_type(4))) float floatx4;  // MFMA acc

__device__ __forceinline__ unsigned short f2bf(float f) {   // fp32 -> bf16 RNE
    unsigned u = __float_as_uint(f);
    u += 0x7FFFu + ((u >> 16) & 1u);
    return (unsigned short)(u >> 16);
}
__device__ __forceinline__ float bf2f(unsigned short h) {
    return __uint_as_float(((unsigned)h) << 16);
}

// Prep: blocks 0..63 element-parallel bf16 hi/lo split, fully coalesced
// 16B-in / 8B-out. Blocks 64..67: fp64-accurate cnorm.
__global__ void vq_prep_kernel(const float* __restrict__ cb,
                               float* __restrict__ cnorm,
                               unsigned short* __restrict__ cb_hi,
                               unsigned short* __restrict__ cb_lo,
                               float* __restrict__ loss_out) {
    const int b = blockIdx.x;
    if (b < 64) {
        const int i = b * 256 + threadIdx.x;     // float4 index, 16384 total
        if (i == 0) loss_out[0] = 0.0f;
        float4 v = ((const float4*)cb)[i];
        unsigned short h0 = f2bf(v.x), h1 = f2bf(v.y),
                       h2 = f2bf(v.z), h3 = f2bf(v.w);
        unsigned short l0 = f2bf(v.x - bf2f(h0)), l1 = f2bf(v.y - bf2f(h1)),
                       l2 = f2bf(v.z - bf2f(h2)), l3 = f2bf(v.w - bf2f(h3));
        uint2 ph = make_uint2((unsigned)h0 | ((unsigned)h1 << 16),
                              (unsigned)h2 | ((unsigned)h3 << 16));
        uint2 pl = make_uint2((unsigned)l0 | ((unsigned)l1 << 16),
                              (unsigned)l2 | ((unsigned)l3 << 16));
        ((uint2*)cb_hi)[i] = ph;                 // coalesced 8B stores
        ((uint2*)cb_lo)[i] = pl;
    } else {
        const int k = (b - 64) * 256 + threadIdx.x;  // 0..1023
        const float4* r4 = (const float4*)(cb + (size_t)k * NC);
        double s = 0.0;
        #pragma unroll
        for (int j = 0; j < 16; ++j) {
            float4 v = r4[j];
            s = fma((double)v.x, (double)v.x, s);
            s = fma((double)v.y, (double)v.y, s);
            s = fma((double)v.z, (double)v.z, s);
            s = fma((double)v.w, (double)v.w, s);
        }
        cnorm[k] = (float)s;
    }
}

// Main, R3: block = 512 threads / 8 waves / 128 pixels -- each wave owns 16
// pixels (ONE MFMA B-set). Memory structure identical to R2 (4-tile
// global_load_lds intervals, inverse-swizzled source, verified conflict-free
// read swizzle). Rationale: R0/R1/R2 counters show >=50% of cycles with no
// issue (MFMA 18% + VALU 31%, HBM 8%, conflicts 0) at only 4 waves/SIMD
// (grid-limited). Halving per-wave pixels at constant block pixel count
// doubles wave count -> 8 waves/SIMD (HW max) to fill dependency stalls
// (ds_read latency -> 6-deep MFMA chains -> fmed3/fmin carried chain).
// Per-wave VGPR state halves, so __launch_bounds__(512,8) (VGPR<=64) holds.
__global__ __launch_bounds__(512, 8) void vq_mfma_kernel(
        const float* __restrict__ z,
        const float* __restrict__ cb,
        const unsigned short* __restrict__ cb_hi,
        const unsigned short* __restrict__ cb_lo,
        const float* __restrict__ cnorm,
        float* __restrict__ zq,
        float* __restrict__ loss_out) {
    // [buf(2)][tile_in_interval(4)*256 + slot(256)] uint4 units, 32 KB.
    // Within one tile: slot = part*128 + row*8 + chunk^(row&7)  (R0 layout).
    __shared__ alignas(16) uint4  abuf[2][1024];
    __shared__ alignas(16) float  cn_lds[NK];   // 4 KB; rescan scratch aliases
    __shared__ int   finidx[PPB];
    __shared__ int   flags[PPB];
    __shared__ float redf[8];

    const int tid = threadIdx.x;
    const int g0  = blockIdx.x * PPB;
    const int bb  = g0 >> 12;
    const int pp0 = g0 & 4095;
    const float* zbase = z  + (size_t)bb * (NC * HW) + pp0;
    float*      zqbase = zq + (size_t)bb * (NC * HW) + pp0;

    // ---- stage cnorm -> LDS (512 threads x float2) ----
    ((float2*)cn_lds)[tid] = ((const float2*)cnorm)[tid];

    const int lane = tid & 63;
    const int w    = tid >> 6;        // wave 0..7 -> pixels w*16..w*16+15
    const int q    = lane >> 4;
    const int pcol = lane & 15;

    // ---- pre-swizzled global sources, 2 LDS slots per thread ----
    // Slot s (0..1023) = tt*256 + part*128 + row*8 + chunk. Thread tid fills
    // slots tid and tid+512 (linear dest = wave-uniform base + lane*16, as
    // global_load_lds requires). Slot chunk field c holds global chunk
    // c^(row&7)  -> XOR goes on the SOURCE (involution, rule #21).
    auto src_of = [&](int s) -> const char* {
        const int tt = s >> 8, part = (s >> 7) & 1;
        const int row = (s >> 3) & 15, chunk = s & 7;
        const char* bp = part ? (const char*)cb_lo : (const char*)cb_hi;
        return bp + tt * 2048 + row * 128 + ((chunk ^ (row & 7)) * 16);
    };
    const char* gsrc1 = src_of(tid);
    const char* gsrc2 = src_of(tid + 512);

    // one 4-tile interval of staging = 8 KB = 512 threads x 16B (x2 slots)
    auto stage_iv = [&](int iv, int buf) {
        __builtin_amdgcn_global_load_lds(
            (const __attribute__((address_space(1))) void*)
                (gsrc1 + (size_t)iv * 8192),
            (__attribute__((address_space(3))) void*)&abuf[buf][tid],
            16, 0, 0);
        __builtin_amdgcn_global_load_lds(
            (const __attribute__((address_space(1))) void*)
                (gsrc2 + (size_t)iv * 8192),
            (__attribute__((address_space(3))) void*)&abuf[buf][tid + 512],
            16, 0, 0);
    };

    stage_iv(0, 0);   // interval 0 in flight; z-loads below cover its latency

    // ---- B fragments straight from global: 16 strided floats per lane ----
    // B[k][n]: n = this wave's pixel (w*16+pcol), k = ks*32 + q*8 + t
    float zraw[2][8];
    #pragma unroll
    for (int ks = 0; ks < 2; ++ks)
        #pragma unroll
        for (int t = 0; t < 8; ++t)
            zraw[ks][t] = zbase[(size_t)(ks * 32 + q * 8 + t) * HW
                                + (w * 16 + pcol)];
    short8 Bh[2], Bl[2];
    #pragma unroll
    for (int ks = 0; ks < 2; ++ks)
        #pragma unroll
        for (int t = 0; t < 8; ++t) {
            float v = -2.0f * zraw[ks][t];
            unsigned short h = f2bf(v);
            unsigned short l = f2bf(v - bf2f(h));
            Bh[ks][t] = (short)h;
            Bl[ks][t] = (short)l;
        }

    // per-lane fixed read offsets (uint4 units within one tile's 256 slots)
    const int ridx0 = pcol * 8 + (q ^ (pcol & 7));        // chunk q
    const int ridx1 = pcol * 8 + ((4 + q) ^ (pcol & 7));  // chunk 4+q

    __syncthreads();   // interval-0 staging drained (compiler vmcnt(0)) + cn_lds

    float B1 = FLT_MAX, B2 = FLT_MAX;
    int   I1 = 0;

    // ---- sweep 64 code tiles as 16 intervals of 4, double-buffered ----
    // Write-after-read safe: buf^1 was last read in interval iv-1, whose end
    // barrier precedes these stores.
    for (int iv = 0; iv < 16; ++iv) {
        if (iv < 15) stage_iv(iv + 1, (iv + 1) & 1);
        const short8* Abase = (const short8*)&abuf[iv & 1][0];
        #pragma unroll
        for (int tt = 0; tt < 4; ++tt) {
            const short8* A = Abase + tt * 256;
            short8 ah0 = A[ridx0];
            short8 ah1 = A[ridx1];
            short8 al0 = A[128 + ridx0];
            short8 al1 = A[128 + ridx1];
            const int tile = iv * 4 + tt;
            const floatx4 cn4 = *(const floatx4*)&cn_lds[tile * 16 + q * 4];
            const int kb = tile * 16 + q * 4;
            // score = cn + (-2z).e :  e_hi*z_hi + e_hi*z_lo + e_lo*z_hi
            floatx4 a0 = __builtin_amdgcn_mfma_f32_16x16x32_bf16(ah0, Bh[0], cn4, 0, 0, 0);
            floatx4 a1 = {0.f, 0.f, 0.f, 0.f};
            a1 = __builtin_amdgcn_mfma_f32_16x16x32_bf16(ah1, Bh[1], a1, 0, 0, 0);
            a0 = __builtin_amdgcn_mfma_f32_16x16x32_bf16(ah0, Bl[0], a0, 0, 0, 0);
            a1 = __builtin_amdgcn_mfma_f32_16x16x32_bf16(ah1, Bl[1], a1, 0, 0, 0);
            a0 = __builtin_amdgcn_mfma_f32_16x16x32_bf16(al0, Bh[0], a0, 0, 0, 0);
            a1 = __builtin_amdgcn_mfma_f32_16x16x32_bf16(al1, Bh[1], a1, 0, 0, 0);

            // C/D layout: code row = q*4+reg, pixel col = lane&15 (verified)
            #pragma unroll
            for (int i = 0; i < 4; ++i) {
                float s = a0[i] + a1[i];
                bool lt = s < B1;                    // strict: first min wins
                I1 = lt ? (kb + i) : I1;
                B2 = __builtin_amdgcn_fmed3f(s, B1, B2);
                B1 = fminf(s, B1);
            }
        }
        __syncthreads();
    }

    // ---- merge top-2 across the 4 lanes sharing each pixel (xor 16,32) ----
    {
        float b1 = B1, b2 = B2;
        int i1 = I1;
        #pragma unroll
        for (int d = 16; d <= 32; d <<= 1) {
            float ob1 = __shfl_xor(b1, d);
            float ob2 = __shfl_xor(b2, d);
            int   oi1 = __shfl_xor(i1, d);
            // second-smallest of {b1,b2,ob1,ob2}; equal b1s -> gap 0 -> rescan
            float nb2 = fminf(fmaxf(b1, ob1), fminf(b2, ob2));
            bool lt = (ob1 < b1) || (ob1 == b1 && oi1 < i1);
            b1 = lt ? ob1 : b1;
            i1 = lt ? oi1 : i1;
            b2 = nb2;
        }
        if (q == 0) {
            const int px = w * 16 + pcol;
            finidx[px] = i1;
            flags[px]  = (b2 - b1 < MARGIN) ? 1 : 0;
        }
    }
    int myflag = 0;
    __syncthreads();
    if (tid < PPB) myflag = flags[tid];
    const int nflag = __syncthreads_count(myflag);

    // ---- rare cooperative exact fp64 rescan ----
    // red_s aliases cn_lds (512 doubles = 4 KB); red_i aliases abuf (free).
    if (nflag > 0) {
        double* red_s = reinterpret_cast<double*>(cn_lds);
        int*    red_i = reinterpret_cast<int*>(&abuf[0][0]);
        for (int p = 0; p < PPB; ++p) {
            if (flags[p]) {
                const float* zp = zbase + p;
                double bd = 1.0e300; int bi = 0;
                #pragma unroll 1
                for (int r = 0; r < 2; ++r) {
                    const int k = tid * 2 + r;
                    const float* rowp = cb + (size_t)k * NC;
                    double s = 0.0;
                    for (int c = 0; c < NC; ++c) {
                        double t = (double)zp[(size_t)c * HW] - (double)rowp[c];
                        s = fma(t, t, s);
                    }
                    if (s < bd) { bd = s; bi = k; }  // k increasing: first min
                }
                red_s[tid] = bd; red_i[tid] = bi;
                __syncthreads();
                if (tid < 64) {
                    double m = red_s[tid]; int mi = red_i[tid];
                    #pragma unroll
                    for (int t = 1; t < 8; ++t) {
                        double om = red_s[tid + 64 * t];
                        int    oi = red_i[tid + 64 * t];
                        if (om < m || (om == m && oi < mi)) { m = om; mi = oi; }
                    }
                    #pragma unroll
                    for (int off = 32; off > 0; off >>= 1) {
                        double om = __shfl_down(m, off);
                        int    oi = __shfl_down(mi, off);
                        if (om < m || (om == m && oi < mi)) { m = om; mi = oi; }
                    }
                    if (tid == 0) finidx[p] = mi;
                }
                __syncthreads();
            }
        }
        __syncthreads();
    }

    // ---- epilogue: gather exact fp32 code row -> z_q, loss SSE ----
    // 4 threads per pixel, 16 channels each.
    {
        const int p  = tid & (PPB - 1);
        const int qq = tid >> 7;             // 0..3
        const int fi = finidx[p];
        const float4* crow4 = (const float4*)(cb + (size_t)fi * NC) + qq * 4;
        float sse = 0.f;
        #pragma unroll
        for (int j = 0; j < 4; ++j) {
            const float4 qv = crow4[j];
            const size_t c0 = (size_t)(qq * 16 + 4 * j) * HW + p;
            const float z0 = zbase[c0];
            const float z1 = zbase[c0 + HW];
            const float z2 = zbase[c0 + 2 * (size_t)HW];
            const float z3 = zbase[c0 + 3 * (size_t)HW];
            zqbase[c0]                  = qv.x;   // coalesced across threads
            zqbase[c0 + HW]             = qv.y;
            zqbase[c0 + 2 * (size_t)HW] = qv.z;
            zqbase[c0 + 3 * (size_t)HW] = qv.w;
            float t0 = qv.x - z0, t1 = qv.y - z1, t2 = qv.z - z2, t3 = qv.w - z3;
            sse = fmaf(t0, t0, sse);
            sse = fmaf(t1, t1, sse);
            sse = fmaf(t2, t2, sse);
            sse = fmaf(t3, t3, sse);
        }
        #pragma unroll
        for (int off = 32; off > 0; off >>= 1) sse += __shfl_down(sse, off);
        if ((tid & 63) == 0) redf[tid >> 6] = sse;
        __syncthreads();
        if (tid == 0) {
            float tot = 0.f;
            #pragma unroll
            for (int r = 0; r < 8; ++r) tot += redf[r];
            atomicAdd(loss_out, tot * (1.25f / (float)TOTAL));
        }
    }
}

extern "C" void kernel_launch(void* const* d_in, const int* in_sizes, int n_in,
                              void* d_out, int out_size, void* d_ws, size_t ws_size,
                              hipStream_t stream) {
    const float* z  = (const float*)d_in[0];   // [32, 64, 64, 64] fp32
    const float* cb = (const float*)d_in[1];   // [1024, 64] fp32
    float* out      = (float*)d_out;           // z_q ++ loss
    float* zqp      = out;
    float* loss     = out + TOTAL;

    // ws: cnorm fp32[1024] | cb_hi bf16[1024*64] | cb_lo bf16[1024*64]
    float* cnorm          = (float*)d_ws;
    unsigned short* cb_hi = (unsigned short*)((char*)d_ws + 4096);
    unsigned short* cb_lo = (unsigned short*)((char*)d_ws + 4096 + NK * NC * 2);

    vq_prep_kernel<<<68, 256, 0, stream>>>(cb, cnorm, cb_hi, cb_lo, loss);
    vq_mfma_kernel<<<NPIX / PPB, 512, 0, stream>>>(z, cb, cb_hi, cb_lo, cnorm,
                                                   zqp, loss);
}